// Round 6
// baseline (142.870 us; speedup 1.0000x reference)
//
#include <hip/hip_runtime.h>

// x shape (8,32,256,256) float32 holding exact integers 0..255; K=3, stride 1, no pad.
#define B_   8
#define C_   32
#define H_   256
#define W_   256
#define BC_  (B_ * C_)
#define HO_  (H_ - 2)           // 254
#define WO_  (W_ - 2)           // 254
#define NIN_  (BC_ * H_ * W_)   // 16,777,216
#define NBINS 256
#define HCOLS 16                // sub-histogram columns (LDS-atomic aliasing ~2-way = free)
#define HBLOCKS 1024            // NIN_/4 = HBLOCKS*256*16 exactly

// Module-owned scratch (d_ws proved unsafe in R1).
__device__ __align__(8) int g_hist[NBINS];
__device__ int g_part[HBLOCKS * NBINS];       // 1 MB partial histograms, plain stores
__device__ unsigned g_x8[NIN_ / 4];           // 16.7 MB packed-u8 copy of x (dword = 4 values)

// R5 post-mortem: all remaining top-5 time is harness poison fills; ours ~60 us vs
// 200 MB floor. R6: second pass reads a u8 copy of x (written here) -> pool fetch
// 74 -> 19 MB. Loads: 8 independent float4s in flight before any atomic (R4 lesson:
// never fan atomics into few global addresses; LDS atomics at <=2-way alias are fine).
__global__ __launch_bounds__(256) void hist_kernel(const float* __restrict__ x) {
    __shared__ int sh[NBINS * HCOLS];   // 16 KB
    const int t = threadIdx.x;
    for (int i = t; i < NBINS * HCOLS; i += 256) sh[i] = 0;
    __syncthreads();

    const int col = t & (HCOLS - 1);
    const float4* x4 = (const float4*)x;
    const int stride = HBLOCKS * 256;          // 262144 float4s
    float4 v[8];
#pragma unroll
    for (int half = 0; half < 2; ++half) {
        const int base = blockIdx.x * 256 + t + half * 8 * stride;
#pragma unroll
        for (int k = 0; k < 8; ++k) v[k] = x4[base + k * stride];  // 8 loads in flight
#pragma unroll
        for (int k = 0; k < 8; ++k) {
            const int ax = (int)v[k].x, ay = (int)v[k].y, az = (int)v[k].z, aw = (int)v[k].w;
            g_x8[base + k * stride] =
                (unsigned)ax | ((unsigned)ay << 8) | ((unsigned)az << 16) | ((unsigned)aw << 24);
            atomicAdd(&sh[ax * HCOLS + col], 1);
            atomicAdd(&sh[ay * HCOLS + col], 1);
            atomicAdd(&sh[az * HCOLS + col], 1);
            atomicAdd(&sh[aw * HCOLS + col], 1);
        }
    }
    __syncthreads();

    // Per-bin column sum, rotated so bank = (17t+c) mod 32 (2-way = free); plain store.
    int s0 = 0;
#pragma unroll
    for (int c = 0; c < HCOLS; ++c) {
        const int cc = (c + t) & (HCOLS - 1);
        s0 += sh[t * HCOLS + cc];
    }
    g_part[blockIdx.x * NBINS + t] = s0;
}

// Single 1024-thread block: tree-reduce 1024 partial rows with PLAIN stores
// (no atomics, no zero kernel). seg s sums rows [256s,256s+256) for its bin.
__global__ __launch_bounds__(1024) void reduce_kernel() {
    __shared__ int acc[4 * NBINS];
    const int t = threadIdx.x;
    const int bin = t & (NBINS - 1);
    const int seg = t >> 8;                    // 0..3
    int s = 0;
#pragma unroll 16
    for (int r = seg * 256; r < seg * 256 + 256; ++r) s += g_part[r * NBINS + bin];
    acc[seg * NBINS + bin] = s;
    __syncthreads();
    if (t < NBINS) g_hist[t] = acc[t] + acc[NBINS + t] + acc[2 * NBINS + t] + acc[3 * NBINS + t];
}

// Block = one (bc, 16-output-row strip). Read u8 image (1 dword = 4 values), ONE
// key-table lookup per input element (key = (count<<8)|value), store key in LDS.
// Compute reads keys stride-1 (2-way alias = free) with 3-register row rotation.
// Argmin on (key & ~255) strict '<' == exact positional first-min (row-major di,dj).
__global__ __launch_bounds__(256) void pool_kernel(float* __restrict__ out) {
    __shared__ int key_s[NBINS];
    __shared__ int tile[18 * W_];   // 18 KB
    const int t = threadIdx.x;
    key_s[t] = (g_hist[t] << 8) | t;
    __syncthreads();

    const int bc = blockIdx.x >> 4;
    const int s  = blockIdx.x & 15;
    const int r0 = s * 16;
    const int rows_out = (r0 + 16 <= HO_) ? 16 : (HO_ - r0);  // 16, last strip 14
    const int rows_in  = rows_out + 2;                        // 18 / 16 (fits H_)

    const unsigned* xin = g_x8 + ((long long)bc * H_ + r0) * (W_ / 4);
    const int nw = rows_in * (W_ / 4);        // 1152 dwords
    for (int idx = t; idx < nw; idx += 256) {
        const unsigned u = xin[idx];
        int4 k;
        k.x = key_s[u & 255];
        k.y = key_s[(u >> 8) & 255];
        k.z = key_s[(u >> 16) & 255];
        k.w = key_s[u >> 24];
        ((int4*)tile)[idx] = k;
    }
    __syncthreads();

    if (t >= WO_) return;   // no further barriers below

    int a0 = tile[t],        a1 = tile[t + 1],        a2 = tile[t + 2];
    int b0 = tile[W_ + t],   b1 = tile[W_ + t + 1],   b2 = tile[W_ + t + 2];
    float* orow = out + ((long long)bc * HO_ + r0) * WO_ + t;
    for (int r = 0; r < rows_out; ++r) {
        const int base = (r + 2) * W_ + t;
        const int c0 = tile[base], c1 = tile[base + 1], c2 = tile[base + 2];
        int best = a0, bm = a0 & ~255;
#define CAND(kk) { const int m = (kk) & ~255; if (m < bm) { bm = m; best = (kk); } }
        CAND(a1) CAND(a2) CAND(b0) CAND(b1) CAND(b2) CAND(c0) CAND(c1) CAND(c2)
#undef CAND
        orow[(long long)r * WO_] = (float)(best & 255);
        a0 = b0; a1 = b1; a2 = b2;
        b0 = c0; b1 = c1; b2 = c2;
    }
}

extern "C" void kernel_launch(void* const* d_in, const int* in_sizes, int n_in,
                              void* d_out, int out_size, void* d_ws, size_t ws_size,
                              hipStream_t stream) {
    const float* x = (const float*)d_in[0];
    float* out = (float*)d_out;
    (void)d_ws; (void)ws_size;

    hist_kernel<<<HBLOCKS, 256, 0, stream>>>(x);
    reduce_kernel<<<1, 1024, 0, stream>>>();
    pool_kernel<<<BC_ * 16, 256, 0, stream>>>(out);
}